// Round 12
// baseline (84.434 us; speedup 1.0000x reference)
//
#include <hip/hip_runtime.h>

#define BB 8
#define CC 128
#define HH 64
#define WW 64
#define K2 9
#define NOFF 18
#define HW 4096          // HH*WW
#define NPIX 32768       // BB*HW
#define NQ 4
#define ROWS 2
#define WPB 4            // waves per block
#define CPW 8            // channels per wave
#define WPAD 20          // padded weight row (18 used, 80 B stride)

#define OFF_BLOCKS 1024  // 256 row-groups x 4 quarters
#define TR_BLOCKS  4096  // 128 p-tiles x 4 c-tiles x 8 b

#define INIT_BLOCKS 1152 // 9*NPIX/256
#define WT_BLOCKS   81   // ceil(18*128*9/256)

__device__ __forceinline__ unsigned short f2bf(float f) {
    unsigned u = __float_as_uint(f);
    unsigned r = u + 0x7FFFu + ((u >> 16) & 1u);   // RNE
    return (unsigned short)(r >> 16);
}

// ---------------------------------------------------------------------------
// K-1: merged prep. Blocks [0,INIT_BLOCKS): sgrid[t][pix] = bias;
// blocks [INIT_BLOCKS, +WT_BLOCKS): weight transpose -> wTp[k=(c,j)][WPAD].
// ---------------------------------------------------------------------------
__global__ __launch_bounds__(256) void prep_kernel(
    const float* __restrict__ offw, const float* __restrict__ offb,
    float2* __restrict__ sgrid, float* __restrict__ wTp)
{
    int bi = blockIdx.x;
    int tid = threadIdx.x;
    if (bi < INIT_BLOCKS) {
        int i = bi * 256 + tid;               // 0 .. 9*NPIX-1
        int t = i >> 15;
        sgrid[i] = make_float2(offb[t], offb[t + K2]);
    } else {
        int i = (bi - INIT_BLOCKS) * 256 + tid;
        if (i < NOFF * CC * 9) {
            int k = i / NOFF, o = i - k * NOFF;
            wTp[k * WPAD + o] = offw[(size_t)o * CC * 9 + k];
        }
    }
}

// ---------------------------------------------------------------------------
// K1: HORIZONTALLY FUSED offset-conv + x transpose (to bf16).
// Offset role: weights read through a LAUNDERED (VGPR) pointer so they go
// down the VECTOR memory path (global_load_dwordx4, vmcnt, in-order, deep
// pipeline) instead of s_load (lgkmcnt, out-of-order, full-drain waits).
// x rows prefetched one channel ahead; halo via shuffles (lgkmcnt only).
// LDS reduce over 4 waves -> atomicAdd into sgrid.
// ---------------------------------------------------------------------------
__global__ __launch_bounds__(256, 4) void fused_offset_transpose_kernel(
    const float* __restrict__ x, const float* __restrict__ wTp,
    float* __restrict__ sgrid, unsigned short* __restrict__ xTb)
{
    __shared__ float lds[NOFF * WPB * 64];   // 18.4 KB
    int bi = blockIdx.x;
    int tid = threadIdx.x;

    if (bi < OFF_BLOCKS) {
        // ------------------- offset-conv role -------------------
        int jx = bi & 255;
        int b = jx & 7;
        int h0 = (jx >> 3) * ROWS;     // 0..62
        int q = bi >> 8;               // 0..3
        int w = tid & 63;
        int wv = __builtin_amdgcn_readfirstlane(tid >> 6);
        int cbase = q * 32 + wv * CPW;

        // launder wTp so derived addresses live in VGPRs -> vector loads
        unsigned long long wp_u = (unsigned long long)(const void*)wTp;
        asm volatile("" : "+v"(wp_u));
        const float* wvec = (const float*)(const void*)wp_u;

        float acc[NOFF][ROWS];
#pragma unroll
        for (int o = 0; o < NOFF; ++o)
#pragma unroll
            for (int r = 0; r < ROWS; ++r) acc[o][r] = 0.f;

        bool wlo = (w == 0), whi = (w == 63);

        // prologue: issue x loads for cc = 0
        float nx[ROWS + 2];
        {
            const float* xp0 = x + ((size_t)(b * CC + cbase)) * HW;
#pragma unroll
            for (int rr = 0; rr < ROWS + 2; ++rr) {
                int hh = h0 + rr - 1;
                nx[rr] = ((unsigned)hh < HH) ? xp0[hh * WW + w] : 0.f;
            }
        }

#pragma unroll 1
        for (int cc = 0; cc < CPW; ++cc) {
            float xc[ROWS + 2], xl[ROWS + 2], xr[ROWS + 2];
#pragma unroll
            for (int rr = 0; rr < ROWS + 2; ++rr) {
                float v = nx[rr];
                xc[rr] = v;
                float vl = __shfl_up(v, 1);
                float vr = __shfl_down(v, 1);
                xl[rr] = wlo ? 0.f : vl;
                xr[rr] = whi ? 0.f : vr;
            }
            // prefetch next channel's x rows (vmcnt, hides under FMAs)
            if (cc + 1 < CPW) {
                const float* xpn = x + ((size_t)(b * CC + cbase + cc + 1)) * HW;
#pragma unroll
                for (int rr = 0; rr < ROWS + 2; ++rr) {
                    int hh = h0 + rr - 1;
                    nx[rr] = ((unsigned)hh < HH) ? xpn[hh * WW + w] : 0.f;
                }
            }
            const float* wrow = wvec + (size_t)(cbase + cc) * 9 * WPAD;
#pragma unroll
            for (int jj = 0; jj < 9; ++jj) {
                const int dh = jj / 3, dc = jj % 3;   // compile-time
                // 18 weights = 4x dwordx4 + 1x dwordx2, vector path
                float4 wA = *(const float4*)(wrow + jj * WPAD + 0);
                float4 wB = *(const float4*)(wrow + jj * WPAD + 4);
                float4 wC = *(const float4*)(wrow + jj * WPAD + 8);
                float4 wD = *(const float4*)(wrow + jj * WPAD + 12);
                float2 wE = *(const float2*)(wrow + jj * WPAD + 16);
                float wr18[NOFF] = {wA.x, wA.y, wA.z, wA.w,
                                    wB.x, wB.y, wB.z, wB.w,
                                    wC.x, wC.y, wC.z, wC.w,
                                    wD.x, wD.y, wD.z, wD.w,
                                    wE.x, wE.y};
                float xvr[ROWS];
#pragma unroll
                for (int r = 0; r < ROWS; ++r)
                    xvr[r] = (dc == 0) ? xl[r + dh]
                           : (dc == 1) ? xc[r + dh] : xr[r + dh];
#pragma unroll
                for (int o = 0; o < NOFF; ++o) {
#pragma unroll
                    for (int r = 0; r < ROWS; ++r)
                        acc[o][r] = fmaf(xvr[r], wr18[o], acc[o][r]);
                }
            }
        }

        for (int r = 0; r < ROWS; ++r) {
#pragma unroll
            for (int o = 0; o < NOFF; ++o)
                lds[(o * WPB + wv) * 64 + w] = acc[o][r];
            __syncthreads();
            for (int item = tid; item < NOFF * 64; item += 256) {
                int o = item >> 6, p = item & 63;
                float s = 0.f;
#pragma unroll
                for (int u = 0; u < WPB; ++u) s += lds[(o * WPB + u) * 64 + p];
                int t = (o < K2) ? o : (o - K2);
                int comp = (o < K2) ? 0 : 1;
                int pix = b * HW + (h0 + r) * 64 + p;
                atomicAdd(&sgrid[((size_t)t * NPIX + pix) * 2 + comp], s);
            }
            __syncthreads();
        }
    } else {
        // ------------------- transpose role (fp32 -> bf16) -------------------
        int bt = bi - OFF_BLOCKS;
        int p0 = (bt & 127) * 32;
        int c0 = ((bt >> 7) & 3) * 32;
        int b  = bt >> 9;
        int tx = tid & 31;
        int ty = tid >> 5;
        float* tile = lds;                 // 32*33 floats
#pragma unroll
        for (int i = 0; i < 4; ++i)
            tile[(ty + i * 8) * 33 + tx] =
                x[((size_t)(b * CC + c0 + ty + i * 8)) * HW + p0 + tx];
        __syncthreads();
#pragma unroll
        for (int i = 0; i < 4; ++i)
            xTb[((size_t)b * HW + p0 + ty + i * 8) * CC + c0 + tx] =
                f2bf(tile[tx * 33 + ty + i * 8]);
    }
}

// ---------------------------------------------------------------------------
// K2: bilinear sample + tap-weighted sum from bf16 xT.
// ---------------------------------------------------------------------------
__global__ __launch_bounds__(256, 4) void sample_kernel(
    const unsigned short* __restrict__ xTb, const float2* __restrict__ sgrid,
    const float* __restrict__ wk, float* __restrict__ out)
{
    __shared__ float4 recW[144];
    __shared__ int2   recI[144];
    __shared__ float  swkT[K2 * CC];
    __shared__ float  acc_s[16 * 132];

    int j = blockIdx.x;            // 0..2047
    int b = j & 7;
    int rem_base = (j >> 3) * 16;
    int h  = rem_base >> 6;
    int w0 = rem_base & 63;
    int tid = threadIdx.x;

    for (int i = tid; i < K2 * CC; i += 256) {
        int c = i / 9, t = i - c * 9;
        swkT[t * CC + c] = wk[i];
    }

    if (tid < 144) {
        int slot = tid & 15;
        int tap  = tid >> 4;
        int rem  = rem_base + slot;
        int pix  = b * HW + rem;
        float2 s = sgrid[(size_t)tap * NPIX + pix];
        int ww2 = rem & 63, hh2 = rem >> 6;
        float base_x = -1.f + (2.f / (WW - 1)) * (float)ww2;
        float base_y = -1.f + (2.f / (HH - 1)) * (float)hh2;
        float gx = ((s.x + base_x + 1.f) * (float)WW - 1.f) * 0.5f;
        float gy = ((s.y + base_y + 1.f) * (float)HH - 1.f) * 0.5f;

        float x0f = floorf(gx), y0f = floorf(gy);
        float wx1 = gx - x0f, wx0 = 1.f - wx1;
        float wy1 = gy - y0f, wy0 = 1.f - wy1;
        int ix0 = (int)x0f, iy0 = (int)y0f;
        int ix1 = ix0 + 1,  iy1 = iy0 + 1;
        float ax0 = ((unsigned)ix0 < WW) ? wx0 : 0.f;
        float ax1 = ((unsigned)ix1 < WW) ? wx1 : 0.f;
        float ay0 = ((unsigned)iy0 < HH) ? wy0 : 0.f;
        float ay1 = ((unsigned)iy1 < HH) ? wy1 : 0.f;
        int cx0 = min(max(ix0, 0), WW - 1), cx1 = min(max(ix1, 0), WW - 1);
        int cy0 = min(max(iy0, 0), HH - 1), cy1 = min(max(iy1, 0), HH - 1);
        int o00 = cy0 * WW + cx0, o10 = cy0 * WW + cx1;
        int o01 = cy1 * WW + cx0, o11 = cy1 * WW + cx1;
        recW[tid] = make_float4(ax0 * ay0, ax1 * ay0, ax0 * ay1, ax1 * ay1);
        recI[tid] = make_int2(o00 | (o10 << 16), o01 | (o11 << 16));
    }
    __syncthreads();

    int c8   = (tid & 15) * 8;
    int slot = tid >> 4;           // 0..15

    const unsigned short* xb = xTb + (size_t)b * HW * CC;

    float acc[8];
#pragma unroll
    for (int i = 0; i < 8; ++i) acc[i] = 0.f;

#pragma unroll
    for (int t = 0; t < K2; ++t) {
        int r = t * 16 + slot;
        float4 wv = recW[r];
        int2   iv = recI[r];
        uint4 u00 = *(const uint4*)(xb + (((iv.x & 0xFFFF) << 7) + c8));
        uint4 u10 = *(const uint4*)(xb + (((iv.x >> 16)     << 7) + c8));
        uint4 u01 = *(const uint4*)(xb + (((iv.y & 0xFFFF) << 7) + c8));
        uint4 u11 = *(const uint4*)(xb + (((iv.y >> 16)     << 7) + c8));
        float4 wkA = *(const float4*)&swkT[t * CC + c8];
        float4 wkB = *(const float4*)&swkT[t * CC + c8 + 4];
        const unsigned* p00 = (const unsigned*)&u00;
        const unsigned* p10 = (const unsigned*)&u10;
        const unsigned* p01 = (const unsigned*)&u01;
        const unsigned* p11 = (const unsigned*)&u11;
#pragma unroll
        for (int g = 0; g < 4; ++g) {            // g = pair of channels
            float v00a = __uint_as_float(p00[g] << 16);
            float v00b = __uint_as_float(p00[g] & 0xFFFF0000u);
            float v10a = __uint_as_float(p10[g] << 16);
            float v10b = __uint_as_float(p10[g] & 0xFFFF0000u);
            float v01a = __uint_as_float(p01[g] << 16);
            float v01b = __uint_as_float(p01[g] & 0xFFFF0000u);
            float v11a = __uint_as_float(p11[g] << 16);
            float v11b = __uint_as_float(p11[g] & 0xFFFF0000u);
            float bila = fmaf(v00a, wv.x, fmaf(v10a, wv.y, fmaf(v01a, wv.z, v11a * wv.w)));
            float bilb = fmaf(v00b, wv.x, fmaf(v10b, wv.y, fmaf(v01b, wv.z, v11b * wv.w)));
            float wka = (g < 2) ? ((g == 0) ? wkA.x : wkA.z)
                                : ((g == 2) ? wkB.x : wkB.z);
            float wkb = (g < 2) ? ((g == 0) ? wkA.y : wkA.w)
                                : ((g == 2) ? wkB.y : wkB.w);
            acc[g * 2]     = fmaf(bila, wka, acc[g * 2]);
            acc[g * 2 + 1] = fmaf(bilb, wkb, acc[g * 2 + 1]);
        }
    }

    *(float4*)&acc_s[slot * 132 + c8]     = make_float4(acc[0], acc[1], acc[2], acc[3]);
    *(float4*)&acc_s[slot * 132 + c8 + 4] = make_float4(acc[4], acc[5], acc[6], acc[7]);
    __syncthreads();
#pragma unroll
    for (int r = 0; r < 8; ++r) {
        int cs   = r * 16 + (tid >> 4);
        int wloc = tid & 15;
        out[((size_t)(b * CC + cs)) * HW + h * WW + w0 + wloc] = acc_s[wloc * 132 + cs];
    }
}

// ---------------------------------------------------------------------------
// Fallback (round-1 pipeline, needs only 2.36 MB ws) — defensive only.
// ---------------------------------------------------------------------------
__global__ __launch_bounds__(256) void offset_grid_kernel_fb(
    const float* __restrict__ x, const float* __restrict__ offw,
    const float* __restrict__ offb, float* __restrict__ grid)
{
    int idx = blockIdx.x * blockDim.x + threadIdx.x;
    if (idx >= NPIX) return;
    int w = idx & 63, h = (idx >> 6) & 63, b = idx >> 12;
    float acc[NOFF];
#pragma unroll
    for (int o = 0; o < NOFF; ++o) acc[o] = offb[o];
    for (int c = 0; c < CC; ++c) {
        const float* xp = x + ((size_t)(b * CC + c)) * HW;
        float xv[9];
#pragma unroll
        for (int dh = -1; dh <= 1; ++dh)
#pragma unroll
            for (int dw = -1; dw <= 1; ++dw) {
                int hh = h + dh, ww2 = w + dw;
                float v = 0.f;
                if (hh >= 0 && hh < HH && ww2 >= 0 && ww2 < WW) v = xp[hh * WW + ww2];
                xv[(dh + 1) * 3 + (dw + 1)] = v;
            }
#pragma unroll
        for (int o = 0; o < NOFF; ++o) {
            const float* wp = offw + (size_t)(o * CC + c) * 9;
#pragma unroll
            for (int jj = 0; jj < 9; ++jj) acc[o] = fmaf(xv[jj], wp[jj], acc[o]);
        }
    }
    float base_x = -1.f + (2.f / (WW - 1)) * (float)w;
    float base_y = -1.f + (2.f / (HH - 1)) * (float)h;
#pragma unroll
    for (int t = 0; t < K2; ++t) {
        float gx = ((acc[t]      + base_x + 1.f) * (float)WW - 1.f) * 0.5f;
        float gy = ((acc[K2 + t] + base_y + 1.f) * (float)HH - 1.f) * 0.5f;
        size_t gi = ((((size_t)b * K2 + t) * HH + h) * WW + w) * 2;
        grid[gi] = gx; grid[gi + 1] = gy;
    }
}

__global__ __launch_bounds__(256) void sample_kernel_fb(
    const float* __restrict__ x, const float* __restrict__ grid,
    const float* __restrict__ wk, float* __restrict__ out)
{
    int idx = blockIdx.x * blockDim.x + threadIdx.x;
    if (idx >= BB * CC * HW) return;
    int w = idx & 63, h = (idx >> 6) & 63;
    int c = (idx / HW) & 127, b = idx / (CC * HW);
    const float* xp = x + ((size_t)(b * CC + c)) * HW;
    const float2* gp = (const float2*)grid;
    float acc = 0.f;
#pragma unroll
    for (int t = 0; t < K2; ++t) {
        float2 g = gp[(((size_t)b * K2 + t)) * HW + h * WW + w];
        float gx = g.x, gy = g.y;
        float x0f = floorf(gx), y0f = floorf(gy);
        float wx1 = gx - x0f, wx0 = 1.f - wx1;
        float wy1 = gy - y0f, wy0 = 1.f - wy1;
        int ix0 = (int)x0f, iy0 = (int)y0f;
        int ix1 = ix0 + 1,  iy1 = iy0 + 1;
        float v00 = 0.f, v10 = 0.f, v01 = 0.f, v11 = 0.f;
        if ((unsigned)iy0 < HH) {
            const float* row = xp + (size_t)iy0 * WW;
            if ((unsigned)ix0 < WW) v00 = row[ix0];
            if ((unsigned)ix1 < WW) v10 = row[ix1];
        }
        if ((unsigned)iy1 < HH) {
            const float* row = xp + (size_t)iy1 * WW;
            if ((unsigned)ix0 < WW) v01 = row[ix0];
            if ((unsigned)ix1 < WW) v11 = row[ix1];
        }
        float bil = v00 * (wx0 * wy0) + v10 * (wx1 * wy0)
                  + v01 * (wx0 * wy1) + v11 * (wx1 * wy1);
        acc = fmaf(bil, wk[c * K2 + t], acc);
    }
    out[idx] = acc;
}

extern "C" void kernel_launch(void* const* d_in, const int* in_sizes, int n_in,
                              void* d_out, int out_size, void* d_ws, size_t ws_size,
                              hipStream_t stream) {
    const float* x    = (const float*)d_in[0];
    const float* offw = (const float*)d_in[1];
    const float* offb = (const float*)d_in[2];
    const float* wwk  = (const float*)d_in[3];
    float* out = (float*)d_out;

    const size_t SGRID_BYTES = (size_t)K2 * NPIX * sizeof(float2);          // 2.36 MB
    const size_t XT_BYTES    = (size_t)NPIX * CC * sizeof(unsigned short);  // 8.39 MB
    const size_t WTP_BYTES   = (size_t)CC * 9 * WPAD * sizeof(float);       // 92 KB
    const size_t NEED = SGRID_BYTES + XT_BYTES + WTP_BYTES;                 // 10.8 MB

    if (ws_size < NEED) {
        float* grid = (float*)d_ws;
        hipLaunchKernelGGL(offset_grid_kernel_fb, dim3(NPIX / 256), dim3(256),
                           0, stream, x, offw, offb, grid);
        hipLaunchKernelGGL(sample_kernel_fb, dim3((BB * CC * HW) / 256), dim3(256),
                           0, stream, x, grid, wwk, out);
        return;
    }

    // ws layout: [sgrid 2.36 MB][xTb 8.39 MB][wTp 92 KB]
    float2*         sgrid = (float2*)d_ws;
    unsigned short* xTb   = (unsigned short*)((char*)d_ws + SGRID_BYTES);
    float*          wTp   = (float*)((char*)d_ws + SGRID_BYTES + XT_BYTES);

    hipLaunchKernelGGL(prep_kernel, dim3(INIT_BLOCKS + WT_BLOCKS), dim3(256),
                       0, stream, offw, offb, sgrid, wTp);
    hipLaunchKernelGGL(fused_offset_transpose_kernel,
                       dim3(OFF_BLOCKS + TR_BLOCKS), dim3(256),
                       0, stream, x, wTp, (float*)sgrid, xTb);
    hipLaunchKernelGGL(sample_kernel, dim3(NPIX / 16), dim3(256),
                       0, stream, xTb, sgrid, wwk, out);
}

// Round 13
// 58.973 us; speedup vs baseline: 1.4317x; 1.4317x over previous
//
#include <hip/hip_runtime.h>

#define BB 8
#define CC 128
#define HH 64
#define WW 64
#define K2 9
#define NOFF 18
#define HW 4096          // HH*WW
#define NPIX 32768       // BB*HW
#define OPAD 32          // o padded to 32 (2 N-tiles)
#define KW 1152          // 9*128 weight row length per o

#define TR_BLOCKS    4096  // 128 p-tiles x 4 c-tiles x 8 b
#define WPREP_BLOCKS 144   // 32*9*128 / 256
#define SAMPLE_BLOCKS 2048

typedef __attribute__((ext_vector_type(8))) short bf16x8;
typedef __attribute__((ext_vector_type(4))) float f32x4;

__device__ __forceinline__ unsigned short f2bf(float f) {
    unsigned u = __float_as_uint(f);
    unsigned r = u + 0x7FFFu + ((u >> 16) & 1u);   // RNE
    return (unsigned short)(r >> 16);
}
__device__ __forceinline__ float bf2f(unsigned short h) {
    return __uint_as_float((unsigned)h << 16);
}

// ---------------------------------------------------------------------------
// K0: fused prep. Blocks [0,TR_BLOCKS): transpose x -> xTb (bf16 hi) and
// xLb (bf16 of residual). Blocks [TR_BLOCKS,+WPREP): weights -> wH/wL in
// [o(32, zero-padded)][j(9)][c(128)] bf16 layout (B^T rows contiguous in k).
// ---------------------------------------------------------------------------
__global__ __launch_bounds__(256) void prep_transpose_kernel(
    const float* __restrict__ x, const float* __restrict__ offw,
    unsigned short* __restrict__ xTb, unsigned short* __restrict__ xLb,
    unsigned short* __restrict__ wH, unsigned short* __restrict__ wL)
{
    __shared__ float tile[32][33];
    int bi = blockIdx.x;
    int tid = threadIdx.x;
    if (bi < TR_BLOCKS) {
        int p0 = (bi & 127) * 32;
        int c0 = ((bi >> 7) & 3) * 32;
        int b  = bi >> 9;
        int tx = tid & 31;
        int ty = tid >> 5;                 // 0..7
#pragma unroll
        for (int i = 0; i < 4; ++i)
            tile[ty + i * 8][tx] =
                x[((size_t)(b * CC + c0 + ty + i * 8)) * HW + p0 + tx];
        __syncthreads();
#pragma unroll
        for (int i = 0; i < 4; ++i) {
            float v = tile[tx][ty + i * 8];
            unsigned short hi = f2bf(v);
            unsigned short lo = f2bf(v - bf2f(hi));
            size_t idx = ((size_t)b * HW + p0 + ty + i * 8) * CC + c0 + tx;
            xTb[idx] = hi;
            xLb[idx] = lo;
        }
    } else {
        int i = (bi - TR_BLOCKS) * 256 + tid;   // 0..36863 = o*1152 + j*128 + c
        int o = i / KW;
        int rem = i - o * KW;
        int j = rem >> 7;
        int c = rem & 127;
        float v = (o < NOFF) ? offw[((size_t)o * CC + c) * K2 + j] : 0.f;
        unsigned short hi = f2bf(v);
        unsigned short lo = f2bf(v - bf2f(hi));
        wH[i] = hi;
        wL[i] = lo;
    }
}

// ---------------------------------------------------------------------------
// K1: offset conv as MFMA im2col GEMM.
// M = pixels (block: one h-row, 64 px = 4 M-tiles), N = 32 (18 real outputs),
// K = 1152 = (j, c). Wave wv owns c-chunk wv (K=32 slices at 9 j's).
// A[pix][k] = xTb/xLb[pix + off_j][c]  (16 B contiguous per lane, boundary
// lanes zeroed). B^T[o][k] = wH/wL[o][j][c] (16 B contiguous per lane).
// Precision: x = xh + xl, w = wh + wl; acc += Ah*Bh + Al*Bh + Ah*Bl.
// LDS reduce over 4 c-chunks, fused bias + coord transform -> sgrid.
// ---------------------------------------------------------------------------
__global__ __launch_bounds__(256, 4) void offset_mfma_kernel(
    const unsigned short* __restrict__ xTb, const unsigned short* __restrict__ xLb,
    const unsigned short* __restrict__ wH, const unsigned short* __restrict__ wL,
    const float* __restrict__ offb, float2* __restrict__ sgrid)
{
    __shared__ float red[4][OPAD][65];   // 33.3 KB
    int jx = blockIdx.x;        // 0..511
    int b = jx & 7;             // XCD-local batch
    int h = jx >> 3;            // 0..63
    int tid = threadIdx.x;
    int l = tid & 63;
    int cw = __builtin_amdgcn_readfirstlane(tid >> 6);   // 0..3 c-chunk
    int c0 = cw * 32;
    int row  = l & 15;          // A: M-row ; B: o-col
    int kseg = l >> 4;          // 0..3 (8 k-elems each)

    f32x4 acc[4][2];
#pragma unroll
    for (int m = 0; m < 4; ++m)
#pragma unroll
        for (int n = 0; n < 2; ++n)
            acc[m][n] = (f32x4){0.f, 0.f, 0.f, 0.f};

    const unsigned short* xh = xTb + (size_t)b * HW * CC;
    const unsigned short* xl = xLb + (size_t)b * HW * CC;

#pragma unroll 1
    for (int j = 0; j < K2; ++j) {
        int dh = j / 3 - 1;
        int dw = (j % 3) - 1;
        bool hok = (unsigned)(h + dh) < HH;
        int koff = j * CC + c0 + kseg * 8;
        bf16x8 Bh0 = *(const bf16x8*)(wH + (size_t)row * KW + koff);
        bf16x8 Bl0 = *(const bf16x8*)(wL + (size_t)row * KW + koff);
        bf16x8 Bh1 = *(const bf16x8*)(wH + (size_t)(row + 16) * KW + koff);
        bf16x8 Bl1 = *(const bf16x8*)(wL + (size_t)(row + 16) * KW + koff);
#pragma unroll
        for (int m = 0; m < 4; ++m) {
            int w  = m * 16 + row;
            int ws = w + dw;
            bool ok = hok && ((unsigned)ws < WW);
            bf16x8 Ah = {}, Al = {};
            if (ok) {
                size_t a = ((size_t)((h + dh) * WW + ws)) * CC + c0 + kseg * 8;
                Ah = *(const bf16x8*)(xh + a);
                Al = *(const bf16x8*)(xl + a);
            }
            acc[m][0] = __builtin_amdgcn_mfma_f32_16x16x32_bf16(Ah, Bh0, acc[m][0], 0, 0, 0);
            acc[m][0] = __builtin_amdgcn_mfma_f32_16x16x32_bf16(Al, Bh0, acc[m][0], 0, 0, 0);
            acc[m][0] = __builtin_amdgcn_mfma_f32_16x16x32_bf16(Ah, Bl0, acc[m][0], 0, 0, 0);
            acc[m][1] = __builtin_amdgcn_mfma_f32_16x16x32_bf16(Ah, Bh1, acc[m][1], 0, 0, 0);
            acc[m][1] = __builtin_amdgcn_mfma_f32_16x16x32_bf16(Al, Bh1, acc[m][1], 0, 0, 0);
            acc[m][1] = __builtin_amdgcn_mfma_f32_16x16x32_bf16(Ah, Bl1, acc[m][1], 0, 0, 0);
        }
    }

    // C/D layout: col = lane&15 (= o), row = (lane>>4)*4 + reg (= px in tile)
#pragma unroll
    for (int m = 0; m < 4; ++m)
#pragma unroll
        for (int n = 0; n < 2; ++n)
#pragma unroll
            for (int r = 0; r < 4; ++r)
                red[cw][n * 16 + row][m * 16 + kseg * 4 + r] = acc[m][n][r];
    __syncthreads();

    for (int item = tid; item < NOFF * 64 / 2 * 2; item += 256) {   // 576 items
        if (item >= 576) break;
        int p = item & 63;
        int t = item >> 6;       // 0..8
        float sx = offb[t]
                 + red[0][t][p] + red[1][t][p] + red[2][t][p] + red[3][t][p];
        float sy = offb[t + K2]
                 + red[0][t + K2][p] + red[1][t + K2][p]
                 + red[2][t + K2][p] + red[3][t + K2][p];
        float base_x = -1.f + (2.f / (WW - 1)) * (float)p;
        float base_y = -1.f + (2.f / (HH - 1)) * (float)h;
        float gx = ((sx + base_x + 1.f) * (float)WW - 1.f) * 0.5f;
        float gy = ((sy + base_y + 1.f) * (float)HH - 1.f) * 0.5f;
        sgrid[(size_t)t * NPIX + b * HW + h * WW + p] = make_float2(gx, gy);
    }
}

// ---------------------------------------------------------------------------
// K2: bilinear sample + tap-weighted sum from bf16 xT (unchanged from R10).
// ---------------------------------------------------------------------------
__global__ __launch_bounds__(256, 4) void sample_kernel(
    const unsigned short* __restrict__ xTb, const float2* __restrict__ sgrid,
    const float* __restrict__ wk, float* __restrict__ out)
{
    __shared__ float4 recW[144];
    __shared__ int2   recI[144];
    __shared__ float  swkT[K2 * CC];
    __shared__ float  acc_s[16 * 132];

    int j = blockIdx.x;            // 0..2047
    int b = j & 7;
    int rem_base = (j >> 3) * 16;
    int h  = rem_base >> 6;
    int w0 = rem_base & 63;
    int tid = threadIdx.x;

    for (int i = tid; i < K2 * CC; i += 256) {
        int c = i / 9, t = i - c * 9;
        swkT[t * CC + c] = wk[i];
    }

    if (tid < 144) {
        int slot = tid & 15;
        int tap  = tid >> 4;
        int rem  = rem_base + slot;
        int pix  = b * HW + rem;
        float2 s = sgrid[(size_t)tap * NPIX + pix];
        float gx = s.x, gy = s.y;

        float x0f = floorf(gx), y0f = floorf(gy);
        float wx1 = gx - x0f, wx0 = 1.f - wx1;
        float wy1 = gy - y0f, wy0 = 1.f - wy1;
        int ix0 = (int)x0f, iy0 = (int)y0f;
        int ix1 = ix0 + 1,  iy1 = iy0 + 1;
        float ax0 = ((unsigned)ix0 < WW) ? wx0 : 0.f;
        float ax1 = ((unsigned)ix1 < WW) ? wx1 : 0.f;
        float ay0 = ((unsigned)iy0 < HH) ? wy0 : 0.f;
        float ay1 = ((unsigned)iy1 < HH) ? wy1 : 0.f;
        int cx0 = min(max(ix0, 0), WW - 1), cx1 = min(max(ix1, 0), WW - 1);
        int cy0 = min(max(iy0, 0), HH - 1), cy1 = min(max(iy1, 0), HH - 1);
        int o00 = cy0 * WW + cx0, o10 = cy0 * WW + cx1;
        int o01 = cy1 * WW + cx0, o11 = cy1 * WW + cx1;
        recW[tid] = make_float4(ax0 * ay0, ax1 * ay0, ax0 * ay1, ax1 * ay1);
        recI[tid] = make_int2(o00 | (o10 << 16), o01 | (o11 << 16));
    }
    __syncthreads();

    int c8   = (tid & 15) * 8;
    int slot = tid >> 4;           // 0..15

    const unsigned short* xb = xTb + (size_t)b * HW * CC;

    float acc[8];
#pragma unroll
    for (int i = 0; i < 8; ++i) acc[i] = 0.f;

#pragma unroll
    for (int t = 0; t < K2; ++t) {
        int r = t * 16 + slot;
        float4 wv = recW[r];
        int2   iv = recI[r];
        uint4 u00 = *(const uint4*)(xb + (((iv.x & 0xFFFF) << 7) + c8));
        uint4 u10 = *(const uint4*)(xb + (((iv.x >> 16)     << 7) + c8));
        uint4 u01 = *(const uint4*)(xb + (((iv.y & 0xFFFF) << 7) + c8));
        uint4 u11 = *(const uint4*)(xb + (((iv.y >> 16)     << 7) + c8));
        float4 wkA = *(const float4*)&swkT[t * CC + c8];
        float4 wkB = *(const float4*)&swkT[t * CC + c8 + 4];
        const unsigned* p00 = (const unsigned*)&u00;
        const unsigned* p10 = (const unsigned*)&u10;
        const unsigned* p01 = (const unsigned*)&u01;
        const unsigned* p11 = (const unsigned*)&u11;
#pragma unroll
        for (int g = 0; g < 4; ++g) {
            float v00a = __uint_as_float(p00[g] << 16);
            float v00b = __uint_as_float(p00[g] & 0xFFFF0000u);
            float v10a = __uint_as_float(p10[g] << 16);
            float v10b = __uint_as_float(p10[g] & 0xFFFF0000u);
            float v01a = __uint_as_float(p01[g] << 16);
            float v01b = __uint_as_float(p01[g] & 0xFFFF0000u);
            float v11a = __uint_as_float(p11[g] << 16);
            float v11b = __uint_as_float(p11[g] & 0xFFFF0000u);
            float bila = fmaf(v00a, wv.x, fmaf(v10a, wv.y, fmaf(v01a, wv.z, v11a * wv.w)));
            float bilb = fmaf(v00b, wv.x, fmaf(v10b, wv.y, fmaf(v01b, wv.z, v11b * wv.w)));
            float wka = (g < 2) ? ((g == 0) ? wkA.x : wkA.z)
                                : ((g == 2) ? wkB.x : wkB.z);
            float wkb = (g < 2) ? ((g == 0) ? wkA.y : wkA.w)
                                : ((g == 2) ? wkB.y : wkB.w);
            acc[g * 2]     = fmaf(bila, wka, acc[g * 2]);
            acc[g * 2 + 1] = fmaf(bilb, wkb, acc[g * 2 + 1]);
        }
    }

    *(float4*)&acc_s[slot * 132 + c8]     = make_float4(acc[0], acc[1], acc[2], acc[3]);
    *(float4*)&acc_s[slot * 132 + c8 + 4] = make_float4(acc[4], acc[5], acc[6], acc[7]);
    __syncthreads();
#pragma unroll
    for (int r = 0; r < 8; ++r) {
        int cs   = r * 16 + (tid >> 4);
        int wloc = tid & 15;
        out[((size_t)(b * CC + cs)) * HW + h * WW + w0 + wloc] = acc_s[wloc * 132 + cs];
    }
}

// ---------------------------------------------------------------------------
// Fallback (round-1 pipeline, needs only 2.36 MB ws) — defensive only.
// ---------------------------------------------------------------------------
__global__ __launch_bounds__(256) void offset_grid_kernel_fb(
    const float* __restrict__ x, const float* __restrict__ offw,
    const float* __restrict__ offb, float* __restrict__ grid)
{
    int idx = blockIdx.x * blockDim.x + threadIdx.x;
    if (idx >= NPIX) return;
    int w = idx & 63, h = (idx >> 6) & 63, b = idx >> 12;
    float acc[NOFF];
#pragma unroll
    for (int o = 0; o < NOFF; ++o) acc[o] = offb[o];
    for (int c = 0; c < CC; ++c) {
        const float* xp = x + ((size_t)(b * CC + c)) * HW;
        float xv[9];
#pragma unroll
        for (int dh = -1; dh <= 1; ++dh)
#pragma unroll
            for (int dw = -1; dw <= 1; ++dw) {
                int hh = h + dh, ww2 = w + dw;
                float v = 0.f;
                if (hh >= 0 && hh < HH && ww2 >= 0 && ww2 < WW) v = xp[hh * WW + ww2];
                xv[(dh + 1) * 3 + (dw + 1)] = v;
            }
#pragma unroll
        for (int o = 0; o < NOFF; ++o) {
            const float* wp = offw + (size_t)(o * CC + c) * 9;
#pragma unroll
            for (int jj = 0; jj < 9; ++jj) acc[o] = fmaf(xv[jj], wp[jj], acc[o]);
        }
    }
    float base_x = -1.f + (2.f / (WW - 1)) * (float)w;
    float base_y = -1.f + (2.f / (HH - 1)) * (float)h;
#pragma unroll
    for (int t = 0; t < K2; ++t) {
        float gx = ((acc[t]      + base_x + 1.f) * (float)WW - 1.f) * 0.5f;
        float gy = ((acc[K2 + t] + base_y + 1.f) * (float)HH - 1.f) * 0.5f;
        size_t gi = ((((size_t)b * K2 + t) * HH + h) * WW + w) * 2;
        grid[gi] = gx; grid[gi + 1] = gy;
    }
}

__global__ __launch_bounds__(256) void sample_kernel_fb(
    const float* __restrict__ x, const float* __restrict__ grid,
    const float* __restrict__ wk, float* __restrict__ out)
{
    int idx = blockIdx.x * blockDim.x + threadIdx.x;
    if (idx >= BB * CC * HW) return;
    int w = idx & 63, h = (idx >> 6) & 63;
    int c = (idx / HW) & 127, b = idx / (CC * HW);
    const float* xp = x + ((size_t)(b * CC + c)) * HW;
    const float2* gp = (const float2*)grid;
    float acc = 0.f;
#pragma unroll
    for (int t = 0; t < K2; ++t) {
        float2 g = gp[(((size_t)b * K2 + t)) * HW + h * WW + w];
        float gx = g.x, gy = g.y;
        float x0f = floorf(gx), y0f = floorf(gy);
        float wx1 = gx - x0f, wx0 = 1.f - wx1;
        float wy1 = gy - y0f, wy0 = 1.f - wy1;
        int ix0 = (int)x0f, iy0 = (int)y0f;
        int ix1 = ix0 + 1,  iy1 = iy0 + 1;
        float v00 = 0.f, v10 = 0.f, v01 = 0.f, v11 = 0.f;
        if ((unsigned)iy0 < HH) {
            const float* row = xp + (size_t)iy0 * WW;
            if ((unsigned)ix0 < WW) v00 = row[ix0];
            if ((unsigned)ix1 < WW) v10 = row[ix1];
        }
        if ((unsigned)iy1 < HH) {
            const float* row = xp + (size_t)iy1 * WW;
            if ((unsigned)ix0 < WW) v01 = row[ix0];
            if ((unsigned)ix1 < WW) v11 = row[ix1];
        }
        float bil = v00 * (wx0 * wy0) + v10 * (wx1 * wy0)
                  + v01 * (wx0 * wy1) + v11 * (wx1 * wy1);
        acc = fmaf(bil, wk[c * K2 + t], acc);
    }
    out[idx] = acc;
}

extern "C" void kernel_launch(void* const* d_in, const int* in_sizes, int n_in,
                              void* d_out, int out_size, void* d_ws, size_t ws_size,
                              hipStream_t stream) {
    const float* x    = (const float*)d_in[0];
    const float* offw = (const float*)d_in[1];
    const float* offb = (const float*)d_in[2];
    const float* wwk  = (const float*)d_in[3];
    float* out = (float*)d_out;

    const size_t SGRID_BYTES = (size_t)K2 * NPIX * sizeof(float2);          // 2.36 MB
    const size_t XT_BYTES    = (size_t)NPIX * CC * sizeof(unsigned short);  // 8.39 MB
    const size_t W_BYTES     = (size_t)OPAD * KW * sizeof(unsigned short);  // 73.7 KB
    const size_t NEED = SGRID_BYTES + 2 * XT_BYTES + 2 * W_BYTES;           // 19.3 MB

    if (ws_size < NEED) {
        float* grid = (float*)d_ws;
        hipLaunchKernelGGL(offset_grid_kernel_fb, dim3(NPIX / 256), dim3(256),
                           0, stream, x, offw, offb, grid);
        hipLaunchKernelGGL(sample_kernel_fb, dim3((BB * CC * HW) / 256), dim3(256),
                           0, stream, x, grid, wwk, out);
        return;
    }

    // ws layout: [sgrid 2.36 MB][xTb 8.39][xLb 8.39][wH 73.7 KB][wL 73.7 KB]
    float2*         sgrid = (float2*)d_ws;
    unsigned short* xTb = (unsigned short*)((char*)d_ws + SGRID_BYTES);
    unsigned short* xLb = (unsigned short*)((char*)d_ws + SGRID_BYTES + XT_BYTES);
    unsigned short* wH  = (unsigned short*)((char*)d_ws + SGRID_BYTES + 2 * XT_BYTES);
    unsigned short* wL  = (unsigned short*)((char*)d_ws + SGRID_BYTES + 2 * XT_BYTES + W_BYTES);

    hipLaunchKernelGGL(prep_transpose_kernel, dim3(TR_BLOCKS + WPREP_BLOCKS), dim3(256),
                       0, stream, x, offw, xTb, xLb, wH, wL);
    hipLaunchKernelGGL(offset_mfma_kernel, dim3(512), dim3(256),
                       0, stream, xTb, xLb, wH, wL, offb, sgrid);
    hipLaunchKernelGGL(sample_kernel, dim3(SAMPLE_BLOCKS), dim3(256),
                       0, stream, xTb, sgrid, wwk, out);
}